// Round 11
// baseline (426.351 us; speedup 1.0000x reference)
//
#include <hip/hip_runtime.h>
#include <hip/hip_bf16.h>
#include <stdint.h>

// MutualCrossAttention: B=8, C=64, H=W=64 -> T=4096 tokens. Inputs FP32, output FP32.
// dir A: Q=x1, K=V=x2 ; dir B: Q=x2, K=V=x1 ; out = outA + outB, layout [b][c][t].
// R11 = R10 (LDS K-staging, 8 waves = dir x pair x ks, 2 blk/CU) +
//  (1) barriers rebalanced: S | sync | wrst+loadst | PV | sync,
//  (2) V loads hoisted to S-phase top (latency hidden under QK),
//  (3) softmax scale folded into xt during prep (exp2 input = raw dot),
//  (4) pbuf XOR bank swizzle (quad0/2 collision removed).
// ws: [0,8MB) xt bf16 token-major {x1,x2}, PRE-SCALED by sqrt(log2(e)/8);
//     [8MB,16MB) vt bf16 c-major {x1,x2}, unscaled.

#define TT 4096
#define CC 64
#define NB 8

typedef float f32x4 __attribute__((ext_vector_type(4)));
typedef float f32x4a __attribute__((ext_vector_type(4), may_alias));
typedef short s16x8 __attribute__((ext_vector_type(8)));  // MFMA operand (register value)
typedef unsigned int u32x4a __attribute__((ext_vector_type(4), may_alias));
typedef float f32a __attribute__((may_alias));

static __device__ __forceinline__ unsigned fbits(float x) { return __float_as_uint(x); }
static __device__ __forceinline__ ushort bf16of(float v) {
    return (ushort)((fbits(v) + 0x8000u) >> 16);
}
static __device__ __forceinline__ unsigned pack2(float a, float b) {
    return __builtin_amdgcn_perm(fbits(b) + 0x8000u, fbits(a) + 0x8000u, 0x07060302u);
}
static __device__ __forceinline__ s16x8 load_frag(const void* p) {
    u32x4a t = *(const u32x4a*)p;
    return __builtin_bit_cast(s16x8, t);
}

// sqrt(log2(e)/8): xt is scaled by this on BOTH Q and K sides -> Q.K = s*log2(e)/8.
#define SQC1 0.4246609177f

// Read fp32 x[inp][b][c][t] in 64x64 tiles; emit bf16 token-major xt[inp][b][t][c]
// (scaled by SQC1, via LDS transpose) and bf16 c-major vt[inp][b][c][t] (unscaled).
__global__ void prep_k(const float* __restrict__ x1, const float* __restrict__ x2,
                       ushort* __restrict__ xt, ushort* __restrict__ vt) {
    const int inp = blockIdx.z, b = blockIdx.y, t0 = blockIdx.x * 64;
    const float* src = (inp == 0 ? x1 : x2) + (size_t)b * CC * TT;
    const size_t plane = (size_t)TT * CC;
    ushort* xd = xt + (size_t)(inp * NB + b) * plane;
    ushort* vd = vt + (size_t)(inp * NB + b) * plane;
    __shared__ ushort lds[64][72];
    const int tid = threadIdx.x;
    const int c  = tid >> 2;
    const int tg = tid & 3;
    const float* srow = src + (size_t)c * TT + t0 + tg * 16;
    unsigned hw[8];
#pragma unroll
    for (int i = 0; i < 4; ++i) {
        f32x4a v = *(const f32x4a*)(srow + i * 4);
        hw[2 * i]     = pack2(v[0], v[1]);
        hw[2 * i + 1] = pack2(v[2], v[3]);
#pragma unroll
        for (int k = 0; k < 4; ++k) lds[tg * 16 + i * 4 + k][c] = bf16of(v[k] * SQC1);
    }
    ushort* vrow = vd + (size_t)c * TT + t0 + tg * 16;
    u32x4a w0 = {hw[0], hw[1], hw[2], hw[3]};
    u32x4a w1 = {hw[4], hw[5], hw[6], hw[7]};
    *(u32x4a*)(vrow) = w0;
    *(u32x4a*)(vrow + 8) = w1;
    __syncthreads();
#pragma unroll
    for (int pass = 0; pass < 2; ++pass) {
        const int t  = (tid >> 3) + pass * 32;
        const int c8 = (tid & 7) * 8;
        u32x4a w = *(const u32x4a*)&lds[t][c8];
        *(u32x4a*)(xd + (size_t)(t0 + t) * CC + c8) = w;
    }
}

// grid = 512 blocks (qt 0..63 x b 0..7), 512 threads = 8 waves.
// wave: dir = w&1, pair = (w>>1)&1 (32-q half of 64), ks = w>>2 (2048-token half).
__global__ __launch_bounds__(512, 4)
void attn_fused_k(const ushort* __restrict__ xt, const ushort* __restrict__ vt,
                  float* __restrict__ out) {
    const int b    = blockIdx.x & 7;
    const int qt   = blockIdx.x >> 3;   // 0..63
    const int tid  = threadIdx.x;
    const int wave = tid >> 6;          // 0..7
    const int lane = tid & 63;
    const int quad = lane >> 4;
    const int l16  = lane & 15;
    const int dir  = wave & 1;
    const int pair = (wave >> 1) & 1;
    const int ks   = wave >> 2;
    const int q0   = qt * 64 + pair * 32;

    const size_t plane = (size_t)TT * CC;
    const ushort* Qb = xt + (size_t)((dir == 0 ? 0 : NB) + b) * plane;  // token-major
    const ushort* Vb = vt + (size_t)((dir == 0 ? NB : 0) + b) * plane;  // c-major

    // K tile-set: 4 tiles (ks x dir), each [tok64][c64] padded to 72 -> 36.9 KB.
    __shared__ __align__(16) ushort ktile[4][64][72];
    // P per wave: [q16][tok64] stride 72, column XOR-swizzled. xbuf overlays post-loop.
    __shared__ __align__(16) ushort pbuf[8][2][16][72];
    __shared__ float lpx[8][2][4][4];
    f32a* xbuf = (f32a*)&pbuf[0][0][0][0];

    // staging role: tile sub = (sk,sd); each thread stages 4 x 16B chunks.
    const int sub = tid >> 7;
    const int sk  = sub >> 1;
    const int sd  = sub & 1;
    const int ch0 = tid & 127;
    const ushort* Ksrc = xt + (size_t)((sd == 0 ? NB : 0) + b) * plane;
    u32x4a st[4];

    auto loadst = [&](int j) {
        const ushort* g = Ksrc + (size_t)(sk * 32 + j) * 64 * CC;
#pragma unroll
        for (int i = 0; i < 4; ++i)
            st[i] = *(const u32x4a*)(g + (size_t)(ch0 + i * 128) * 8);
    };
    auto wrst = [&]() {
        unsigned* d = (unsigned*)&ktile[sub][0][0];
#pragma unroll
        for (int i = 0; i < 4; ++i) {
            const int c = ch0 + i * 128;
            *(u32x4a*)&d[(c >> 3) * 36 + (c & 7) * 4] = st[i];
        }
    };

    // Q a-frags: A[m=q=l16][k=c=quad*8+j], loaded once (pre-scaled in prep).
    s16x8 qf[2][2];
#pragma unroll
    for (int rb = 0; rb < 2; ++rb)
#pragma unroll
        for (int ch = 0; ch < 2; ++ch)
            qf[rb][ch] = load_frag(Qb + (size_t)(q0 + rb * 16 + l16) * CC + ch * 32 + quad * 8);

    f32x4 accO[2][4];
#pragma unroll
    for (int rb = 0; rb < 2; ++rb)
#pragma unroll
        for (int ct = 0; ct < 4; ++ct) accO[rb][ct] = (f32x4){0.f, 0.f, 0.f, 0.f};
    float lp[2][4];
#pragma unroll
    for (int rb = 0; rb < 2; ++rb)
#pragma unroll
        for (int r = 0; r < 4; ++r) lp[rb][r] = 0.f;

    const ushort* vp  = Vb + (size_t)l16 * TT + quad * 8;
    const ushort* kfb = &ktile[ks * 2 + dir][0][0];
    const int wsw = (quad >> 1) * 16;   // pbuf write column swizzle
    const int rsw = (l16 >> 3) * 16;    // pbuf read column swizzle

    // Prologue: stage ktile(0); issue loadst(1).
    loadst(0);
    wrst();
    loadst(1);
    __syncthreads();

#pragma unroll 1
    for (int j = 0; j < 32; ++j) {
        const int k0 = (ks * 32 + j) * 64;
        // (a) V loads issued first: ~whole S-phase hides their L1/L2 latency.
        s16x8 vf[2][4];
#pragma unroll
        for (int ch2 = 0; ch2 < 2; ++ch2)
#pragma unroll
            for (int ct = 0; ct < 4; ++ct)
                vf[ch2][ct] = load_frag(vp + (size_t)(ct * 16) * TT + k0 + ch2 * 32);

        // (b) S = Q·K^T from staged ktile; P -> pbuf (swizzled columns).
#pragma unroll
        for (int nt = 0; nt < 4; ++nt) {
            const ushort* kr = kfb + (size_t)(nt * 16 + l16) * 72 + quad * 8;
            s16x8 kf0 = load_frag(kr);
            s16x8 kf1 = load_frag(kr + 32);
#pragma unroll
            for (int rb = 0; rb < 2; ++rb) {
                f32x4 s = (f32x4){0.f, 0.f, 0.f, 0.f};
                s = __builtin_amdgcn_mfma_f32_16x16x32_bf16(qf[rb][0], kf0, s, 0, 0, 0);
                s = __builtin_amdgcn_mfma_f32_16x16x32_bf16(qf[rb][1], kf1, s, 0, 0, 0);
#pragma unroll
                for (int r = 0; r < 4; ++r) {
                    float p = __builtin_amdgcn_exp2f(s[r]);  // scale folded into xt
                    lp[rb][r] += p;
                    pbuf[wave][rb][quad * 4 + r][(nt * 16 + l16) ^ wsw] = bf16of(p);
                }
            }
        }
        __syncthreads();                       // all waves done reading ktile(j)
        if (j < 31) {
            wrst();                            // write ktile(j+1)
            if (j < 30) loadst(j + 2);         // refill staging regs
        }
        // (c) PV overlaps the staging-write drain; no ktile dependency.
#pragma unroll
        for (int ch2 = 0; ch2 < 2; ++ch2) {
            s16x8 pf[2];
#pragma unroll
            for (int rb = 0; rb < 2; ++rb)
                pf[rb] = load_frag(&pbuf[wave][rb][l16][(ch2 * 32 + quad * 8) ^ rsw]);
#pragma unroll
            for (int ct = 0; ct < 4; ++ct)
#pragma unroll
                for (int rb = 0; rb < 2; ++rb)
                    accO[rb][ct] = __builtin_amdgcn_mfma_f32_16x16x32_bf16(
                        pf[rb], vf[ch2][ct], accO[rb][ct], 0, 0, 0);
        }
        if (j < 31) __syncthreads();           // ktile(j+1) visible for next S
    }

    // Wave-local denom: butterfly over l16 bits; publish to lpx.
#pragma unroll
    for (int rb = 0; rb < 2; ++rb)
#pragma unroll
        for (int r = 0; r < 4; ++r) {
            float l = lp[rb][r];
            l += __shfl_xor(l, 1);
            l += __shfl_xor(l, 2);
            l += __shfl_xor(l, 4);
            l += __shfl_xor(l, 8);
            lp[rb][r] = l;
            if (l16 == 0) lpx[wave][rb][quad][r] = l;
        }
    __syncthreads();  // pbuf dead -> xbuf overlay safe; lpx visible
    float inv[2][4];
#pragma unroll
    for (int rb = 0; rb < 2; ++rb)
#pragma unroll
        for (int r = 0; r < 4; ++r)
            inv[rb][r] = __builtin_amdgcn_rcpf(lp[rb][r] + lpx[wave ^ 4][rb][quad][r]);

    // 4-phase merge over g = (ks,dir) into xbuf[pair]; g==0 stores.
    const int g = ((wave >> 2) << 1) | dir;
#pragma unroll 1
    for (int ph = 3; ph >= 1; --ph) {
        if (g == ph) {
#pragma unroll
            for (int rb = 0; rb < 2; ++rb)
#pragma unroll
                for (int ct = 0; ct < 4; ++ct)
#pragma unroll
                    for (int r = 0; r < 4; ++r) {
                        const int slot = (pair * 32 + rb * 16 + ct * 4 + r) * 64 + lane;
                        float v = accO[rb][ct][r] * inv[rb][r];
                        if (ph == 3) xbuf[slot] = v;
                        else xbuf[slot] += v;
                    }
        }
        __syncthreads();
    }
    if (g == 0) {
        float* ob = out + (size_t)b * plane;
#pragma unroll
        for (int rb = 0; rb < 2; ++rb)
#pragma unroll
            for (int ct = 0; ct < 4; ++ct) {
                f32x4a v;
#pragma unroll
                for (int r = 0; r < 4; ++r)
                    v[r] = accO[rb][ct][r] * inv[rb][r] +
                           xbuf[(pair * 32 + rb * 16 + ct * 4 + r) * 64 + lane];
                *(f32x4a*)(ob + (size_t)(ct * 16 + l16) * TT + q0 + rb * 16 + quad * 4) = v;
            }
    }
}

extern "C" void kernel_launch(void* const* d_in, const int* in_sizes, int n_in,
                              void* d_out, int out_size, void* d_ws, size_t ws_size,
                              hipStream_t stream) {
    const float* x1 = (const float*)d_in[0];
    const float* x2 = (const float*)d_in[1];
    ushort* xt = (ushort*)d_ws;                              // 8 MB
    ushort* vt = (ushort*)d_ws + (size_t)2 * NB * TT * CC;   // 8 MB

    hipLaunchKernelGGL(prep_k, dim3(TT / 64, NB, 2), dim3(256), 0, stream, x1, x2, xt, vt);
    hipLaunchKernelGGL(attn_fused_k, dim3(64 * NB), dim3(512), 0, stream,
                       xt, vt, (float*)d_out);
}

// Round 12
// 222.212 us; speedup vs baseline: 1.9187x; 1.9187x over previous
//
#include <hip/hip_runtime.h>
#include <hip/hip_bf16.h>
#include <stdint.h>

// MutualCrossAttention: B=8, C=64, H=W=64 -> T=4096 tokens. Inputs FP32, output FP32.
// dir A: Q=x1, K=V=x2 ; dir B: Q=x2, K=V=x1 ; out = outA + outB, layout [b][c][t].
// R12 = R10 skeleton (LDS K-staging, 8 waves = dir x pair x ks, 2 blk/CU) with the
// S^T composition (proved correct in R3-R5: A=K,B=Q then A=V,B=P^T):
//   - P^T C/D layout gives 4 CONSECUTIVE tokens/lane -> pbuf written as b64,
//     read as b128; stride-72 rows distribute both at the bank-minimum (0 excess).
//   - lp is one scalar per lane (q = l16 column), butterflied over quads.
//   - O^T epilogue: row=c, col=q -> scalar f32 stores coalesced over l16.
// PV(j-1) fills the staging-barrier gap; vf transient (no hoisted arrays -> no spill).
// ws: [0,8MB) xt bf16 token-major {x1,x2} PRE-SCALED by sqrt(log2(e)/8);
//     [8MB,16MB) vt bf16 c-major {x1,x2} unscaled.

#define TT 4096
#define CC 64
#define NB 8

typedef float f32x4 __attribute__((ext_vector_type(4)));
typedef float f32x4a __attribute__((ext_vector_type(4), may_alias));
typedef short s16x8 __attribute__((ext_vector_type(8)));
typedef unsigned int u32x2a __attribute__((ext_vector_type(2), may_alias));
typedef unsigned int u32x4a __attribute__((ext_vector_type(4), may_alias));
typedef float f32a __attribute__((may_alias));

static __device__ __forceinline__ unsigned fbits(float x) { return __float_as_uint(x); }
static __device__ __forceinline__ ushort bf16of(float v) {
    return (ushort)((fbits(v) + 0x8000u) >> 16);
}
static __device__ __forceinline__ unsigned pack2(float a, float b) {
    return __builtin_amdgcn_perm(fbits(b) + 0x8000u, fbits(a) + 0x8000u, 0x07060302u);
}
static __device__ __forceinline__ s16x8 load_frag(const void* p) {
    u32x4a t = *(const u32x4a*)p;
    return __builtin_bit_cast(s16x8, t);
}

#define SQC1 0.4246609177f  // sqrt(log2(e)/8), applied to xt on both Q and K sides

__global__ void prep_k(const float* __restrict__ x1, const float* __restrict__ x2,
                       ushort* __restrict__ xt, ushort* __restrict__ vt) {
    const int inp = blockIdx.z, b = blockIdx.y, t0 = blockIdx.x * 64;
    const float* src = (inp == 0 ? x1 : x2) + (size_t)b * CC * TT;
    const size_t plane = (size_t)TT * CC;
    ushort* xd = xt + (size_t)(inp * NB + b) * plane;
    ushort* vd = vt + (size_t)(inp * NB + b) * plane;
    __shared__ ushort lds[64][72];
    const int tid = threadIdx.x;
    const int c  = tid >> 2;
    const int tg = tid & 3;
    const float* srow = src + (size_t)c * TT + t0 + tg * 16;
    unsigned hw[8];
#pragma unroll
    for (int i = 0; i < 4; ++i) {
        f32x4a v = *(const f32x4a*)(srow + i * 4);
        hw[2 * i]     = pack2(v[0], v[1]);
        hw[2 * i + 1] = pack2(v[2], v[3]);
#pragma unroll
        for (int k = 0; k < 4; ++k) lds[tg * 16 + i * 4 + k][c] = bf16of(v[k] * SQC1);
    }
    ushort* vrow = vd + (size_t)c * TT + t0 + tg * 16;
    u32x4a w0 = {hw[0], hw[1], hw[2], hw[3]};
    u32x4a w1 = {hw[4], hw[5], hw[6], hw[7]};
    *(u32x4a*)(vrow) = w0;
    *(u32x4a*)(vrow + 8) = w1;
    __syncthreads();
#pragma unroll
    for (int pass = 0; pass < 2; ++pass) {
        const int t  = (tid >> 3) + pass * 32;
        const int c8 = (tid & 7) * 8;
        u32x4a w = *(const u32x4a*)&lds[t][c8];
        *(u32x4a*)(xd + (size_t)(t0 + t) * CC + c8) = w;
    }
}

// grid = 512 blocks (qt 0..63 x b 0..7), 512 threads = 8 waves.
// wave: dir = w&1, pair = (w>>1)&1, ks = w>>2 (2048-token half).
__global__ __launch_bounds__(512, 4)
void attn_fused_k(const ushort* __restrict__ xt, const ushort* __restrict__ vt,
                  float* __restrict__ out) {
    const int b    = blockIdx.x & 7;
    const int qt   = blockIdx.x >> 3;
    const int tid  = threadIdx.x;
    const int wave = tid >> 6;
    const int lane = tid & 63;
    const int quad = lane >> 4;
    const int l16  = lane & 15;
    const int dir  = wave & 1;
    const int pair = (wave >> 1) & 1;
    const int ks   = wave >> 2;
    const int q0   = qt * 64 + pair * 32;

    const size_t plane = (size_t)TT * CC;
    const ushort* Qb = xt + (size_t)((dir == 0 ? 0 : NB) + b) * plane;  // token-major
    const ushort* Vb = vt + (size_t)((dir == 0 ? NB : 0) + b) * plane;  // c-major

    __shared__ __align__(16) ushort ktile[4][64][72];      // 36.9 KB
    __shared__ __align__(16) ushort pbuf[8][2][16][72];    // 36.9 KB (q rows, tok cols)
    __shared__ float lpx[8][2][16];                        // 1 KB
    f32a* xbuf = (f32a*)&pbuf[0][0][0][0];                 // 16 KB overlay, post-loop

    // staging role: tile sub = (sk,sd); 4 x 16B chunks per thread.
    const int sub = tid >> 7;
    const int sk  = sub >> 1;
    const int sd  = sub & 1;
    const int ch0 = tid & 127;
    const ushort* Ksrc = xt + (size_t)((sd == 0 ? NB : 0) + b) * plane;
    u32x4a st[4];

    auto loadst = [&](int j) {
        const ushort* g = Ksrc + (size_t)(sk * 32 + j) * 64 * CC;
#pragma unroll
        for (int i = 0; i < 4; ++i)
            st[i] = *(const u32x4a*)(g + (size_t)(ch0 + i * 128) * 8);
    };
    auto wrst = [&]() {
        unsigned* d = (unsigned*)&ktile[sub][0][0];
#pragma unroll
        for (int i = 0; i < 4; ++i) {
            const int c = ch0 + i * 128;
            *(u32x4a*)&d[(c >> 3) * 36 + (c & 7) * 4] = st[i];
        }
    };

    // Q b-frags: B[n=q=l16][k=c=quad*8+j], pre-scaled.
    s16x8 qf[2][2];
#pragma unroll
    for (int rb = 0; rb < 2; ++rb)
#pragma unroll
        for (int ch = 0; ch < 2; ++ch)
            qf[rb][ch] = load_frag(Qb + (size_t)(q0 + rb * 16 + l16) * CC + ch * 32 + quad * 8);

    f32x4 accO[2][4];  // O^T partial: row=c=quad*4+r (+ct*16), col=q=l16 (+rb*16)
#pragma unroll
    for (int rb = 0; rb < 2; ++rb)
#pragma unroll
        for (int ct = 0; ct < 4; ++ct) accO[rb][ct] = (f32x4){0.f, 0.f, 0.f, 0.f};
    float lp[2] = {0.f, 0.f};

    const ushort* vp  = Vb + (size_t)l16 * TT + quad * 8;
    const ushort* kfb = &ktile[ks * 2 + dir][0][0];

    // S^T(j): A = K from staged ktile [m=tok=mt*16+l16][k=c], B = Q.
    // D[row=tok=quad*4+r (+mt*16)][col=q=l16] -> 4 consecutive tokens -> b64 P write.
    auto Sphase = [&]() {
#pragma unroll
        for (int mt = 0; mt < 4; ++mt) {
            const ushort* kr = kfb + (size_t)(mt * 16 + l16) * 72 + quad * 8;
            s16x8 kf0 = load_frag(kr);
            s16x8 kf1 = load_frag(kr + 32);
#pragma unroll
            for (int rb = 0; rb < 2; ++rb) {
                f32x4 s = (f32x4){0.f, 0.f, 0.f, 0.f};
                s = __builtin_amdgcn_mfma_f32_16x16x32_bf16(kf0, qf[rb][0], s, 0, 0, 0);
                s = __builtin_amdgcn_mfma_f32_16x16x32_bf16(kf1, qf[rb][1], s, 0, 0, 0);
                float p0 = __builtin_amdgcn_exp2f(s[0]);
                float p1 = __builtin_amdgcn_exp2f(s[1]);
                float p2 = __builtin_amdgcn_exp2f(s[2]);
                float p3 = __builtin_amdgcn_exp2f(s[3]);
                lp[rb] += (p0 + p1) + (p2 + p3);
                u32x2a w;
                w[0] = pack2(p0, p1);
                w[1] = pack2(p2, p3);
                *(u32x2a*)&pbuf[wave][rb][l16][mt * 16 + quad * 4] = w;
            }
        }
    };
    // PV(j): A = V [m=c=l16(+ct*16)][k=tok], B = P^T [n=q=l16][k=tok] (b128 LDS).
    auto PVphase = [&](int j) {
        const int k0 = (ks * 32 + j) * 64;
#pragma unroll
        for (int ch2 = 0; ch2 < 2; ++ch2) {
            s16x8 pf[2];
#pragma unroll
            for (int rb = 0; rb < 2; ++rb)
                pf[rb] = load_frag(&pbuf[wave][rb][l16][ch2 * 32 + quad * 8]);
#pragma unroll
            for (int ct = 0; ct < 4; ++ct) {
                s16x8 vf = load_frag(vp + (size_t)(ct * 16) * TT + k0 + ch2 * 32);
#pragma unroll
                for (int rb = 0; rb < 2; ++rb)
                    accO[rb][ct] = __builtin_amdgcn_mfma_f32_16x16x32_bf16(
                        vf, pf[rb], accO[rb][ct], 0, 0, 0);
            }
        }
    };

    // Pipeline: S(j) alone in one barrier gap; wrst/loadst + PV(j-1) in the other.
    loadst(0);
    wrst();
    loadst(1);
    __syncthreads();
    Sphase();            // j = 0
#pragma unroll 1
    for (int j = 1; j < 32; ++j) {
        __syncthreads();           // all waves done reading ktile(j-1)
        wrst();                    // write ktile(j)
        if (j < 31) loadst(j + 1);
        PVphase(j - 1);            // wave-private pbuf; overlaps staging drain
        __syncthreads();           // ktile(j) visible
        Sphase();                  // S(j), overwrites pbuf AFTER PV consumed it
    }
    PVphase(31);

    // Denominator: quads hold disjoint token subsets for col q=l16.
    float inv[2];
#pragma unroll
    for (int rb = 0; rb < 2; ++rb) {
        float l = lp[rb];
        l += __shfl_xor(l, 16);
        l += __shfl_xor(l, 32);
        lp[rb] = l;
        if (lane < 16) lpx[wave][rb][l16] = l;
    }
    __syncthreads();  // pbuf dead -> xbuf overlay safe; lpx visible
#pragma unroll
    for (int rb = 0; rb < 2; ++rb)
        inv[rb] = __builtin_amdgcn_rcpf(lp[rb] + lpx[wave ^ 4][rb][l16]);

    // 4-phase merge over g = (ks,dir) into xbuf[pair]; g==0 stores.
    const int g = (ks << 1) | dir;
#pragma unroll 1
    for (int ph = 3; ph >= 1; --ph) {
        if (g == ph) {
#pragma unroll
            for (int rb = 0; rb < 2; ++rb)
#pragma unroll
                for (int ct = 0; ct < 4; ++ct)
#pragma unroll
                    for (int r = 0; r < 4; ++r) {
                        const int slot = (pair * 32 + rb * 16 + ct * 4 + r) * 64 + lane;
                        float v = accO[rb][ct][r] * inv[rb];
                        if (ph == 3) xbuf[slot] = v;
                        else xbuf[slot] += v;
                    }
        }
        __syncthreads();
    }
    if (g == 0) {
        float* ob = out + (size_t)b * plane;
#pragma unroll
        for (int rb = 0; rb < 2; ++rb)
#pragma unroll
            for (int ct = 0; ct < 4; ++ct)
#pragma unroll
                for (int r = 0; r < 4; ++r) {
                    float v = accO[rb][ct][r] * inv[rb] +
                              xbuf[(pair * 32 + rb * 16 + ct * 4 + r) * 64 + lane];
                    // out[c = ct*16+quad*4+r][t = q0+rb*16+l16]: coalesced over l16
                    ob[(size_t)(ct * 16 + quad * 4 + r) * TT + q0 + rb * 16 + l16] = v;
                }
    }
}

extern "C" void kernel_launch(void* const* d_in, const int* in_sizes, int n_in,
                              void* d_out, int out_size, void* d_ws, size_t ws_size,
                              hipStream_t stream) {
    const float* x1 = (const float*)d_in[0];
    const float* x2 = (const float*)d_in[1];
    ushort* xt = (ushort*)d_ws;                              // 8 MB
    ushort* vt = (ushort*)d_ws + (size_t)2 * NB * TT * CC;   // 8 MB

    hipLaunchKernelGGL(prep_k, dim3(TT / 64, NB, 2), dim3(256), 0, stream, x1, x2, xt, vt);
    hipLaunchKernelGGL(attn_fused_k, dim3(64 * NB), dim3(512), 0, stream,
                       xt, vt, (float*)d_out);
}